// Round 7
// baseline (8577.287 us; speedup 1.0000x reference)
//
#include <hip/hip_runtime.h>
#include <hip/hip_bf16.h>

#define NT 128
#define NE 256
#define ND 256

__device__ __forceinline__ float fast_tanh(float x) {
    const float e = __expf(2.f * x);
    return __builtin_fmaf(-2.f, __fdividef(1.f, e + 1.f), 1.f);
}
__device__ __forceinline__ float fast_sigm(float x) {
    return __fdividef(1.f, 1.f + __expf(-x));
}
__device__ __forceinline__ void fma4(float4& a, float s, const float4 b) {
    a.x += s * b.x; a.y += s * b.y; a.z += s * b.z; a.w += s * b.w;
}
__device__ __forceinline__ unsigned short f2bf(float f) {   // RNE
    unsigned int u = __float_as_uint(f);
    return (unsigned short)((u + 0x7FFFu + ((u >> 16) & 1u)) >> 16);
}
// unpack 4 bf16 (packed in uint2) -> float4. elem0 = low half of .x
__device__ __forceinline__ float4 unpk(uint2 u) {
    float4 r;
    r.x = __uint_as_float(u.x << 16);
    r.y = __uint_as_float(u.x & 0xFFFF0000u);
    r.z = __uint_as_float(u.y << 16);
    r.w = __uint_as_float(u.y & 0xFFFF0000u);
    return r;
}
__device__ __forceinline__ uint2 pk4(float4 v) {
    uint2 u;
    u.x = (unsigned int)f2bf(v.x) | ((unsigned int)f2bf(v.y) << 16);
    u.y = (unsigned int)f2bf(v.z) | ((unsigned int)f2bf(v.w) << 16);
    return u;
}

// ---- prep: w1 hc-half -> bf16 (blocks 0..511); bias sum (block 512)
__global__ __launch_bounds__(256) void prep_w1_bias(
    const float* __restrict__ w1, const float* __restrict__ bih,
    const float* __restrict__ bhh, unsigned short* __restrict__ w1bf,
    float* __restrict__ biasg)
{
    const int t = threadIdx.x, blk = blockIdx.x;
    if (blk < 512) {
        const int idx = blk * 256 + t;
        w1bf[idx] = f2bf(w1[idx]);
    } else {
        for (int g = t; g < 1024; g += 256) biasg[g] = bih[g] + bhh[g];
    }
}

// ---- transpose whh[1024][256] -> whhT_bf16[256][1024]
__global__ __launch_bounds__(256) void transpose_whh_bf(
    const float* __restrict__ whh, unsigned short* __restrict__ whhT)
{
    __shared__ float tile[64][65];
    const int t = threadIdx.x;
    const int bi = blockIdx.x >> 2;
    const int bj = blockIdx.x & 3;
    #pragma unroll
    for (int k = 0; k < 16; ++k) {
        const int idx = k * 256 + t, r = idx >> 6, c = idx & 63;
        tile[r][c] = whh[(size_t)(bi * 64 + r) * 256 + bj * 64 + c];
    }
    __syncthreads();
    #pragma unroll
    for (int k = 0; k < 16; ++k) {
        const int idx = k * 256 + t, r = idx >> 6, c = idx & 63;
        whhT[(size_t)(bj * 64 + r) * 1024 + bi * 64 + c] = f2bf(tile[c][r]);
    }
}

// ---- pre[row][j] = b1[j] + sum_i enc[row][i] * attn_w1[512+i][j]; bf16 out
__global__ __launch_bounds__(256) void pre_enc_kernel(
    const float* __restrict__ enc, const float* __restrict__ w1,
    const float* __restrict__ b1, unsigned short* __restrict__ prebf)
{
    __shared__ __align__(16) float encs[8][256];
    const int t = threadIdx.x;
    const size_t r0 = (size_t)blockIdx.x * 8;
    for (int k = t; k < 512; k += 256) {
        const int rl = k >> 6, i4 = (k & 63) * 4;
        *(float4*)&encs[rl][i4] = *(const float4*)(enc + (r0 + rl) * 256 + i4);
    }
    __syncthreads();
    const int rl = t >> 5;
    const int j0 = (t & 31) * 8;
    float4 a0 = *(const float4*)(b1 + j0);
    float4 a1 = *(const float4*)(b1 + j0 + 4);
    const float* wp = w1 + (size_t)512 * 256 + j0;
    #pragma unroll 2
    for (int i = 0; i < 256; i += 4) {
        const float4 e4 = *(const float4*)&encs[rl][i];
        const float* w_i = wp + (size_t)i * 256;
        float4 wa, wb;
        wa = *(const float4*)(w_i);        wb = *(const float4*)(w_i + 4);
        fma4(a0, e4.x, wa); fma4(a1, e4.x, wb);
        wa = *(const float4*)(w_i + 256);  wb = *(const float4*)(w_i + 260);
        fma4(a0, e4.y, wa); fma4(a1, e4.y, wb);
        wa = *(const float4*)(w_i + 512);  wb = *(const float4*)(w_i + 516);
        fma4(a0, e4.z, wa); fma4(a1, e4.z, wb);
        wa = *(const float4*)(w_i + 768);  wb = *(const float4*)(w_i + 772);
        fma4(a0, e4.w, wa); fma4(a1, e4.w, wb);
    }
    unsigned short* op = prebf + (r0 + rl) * 256 + j0;
    const uint2 u0 = pk4(a0), u1 = pk4(a1);
    *(uint2*)op = u0;
    *(uint2*)(op + 4) = u1;
}

// ---- main scan: 256 WGs x 1024 threads, 2 batch rows per WG.
// enc fully in LDS (128KB bf16); pre in 32 regs/thread; part shrunk to 16KB.
// Peak live regs ~60 so the design fits even a 64-VGPR budget (rounds 5/6
// showed launch_bounds cannot raise the cap; 48 staged regs were spilled).
__global__ __launch_bounds__(1024)
__attribute__((amdgpu_waves_per_eu(4, 4)))
void decoder_main(
    const float* __restrict__ enc, const float* __restrict__ yhist,
    const unsigned short* __restrict__ prebf,
    const unsigned short* __restrict__ w1bf,
    const float* __restrict__ w2g, const unsigned short* __restrict__ whhT,
    const float* __restrict__ wih, const float* __restrict__ biasg,
    const float* __restrict__ fcw, const float* __restrict__ fcb,
    const float* __restrict__ fcfw, const float* __restrict__ fcfb,
    float* __restrict__ out)
{
    __shared__ __align__(16) unsigned short encs[2][128][256]; // 128KB
    __shared__ __align__(16) float part[4096];                 // 16KB union A/C/E
    __shared__ __align__(16) float hc2[512][2];                // 4KB [i][r]
    __shared__ __align__(16) float prehc[2][256];              // 2KB
    __shared__ __align__(16) float scores[2][128];             // 1KB
    __shared__ __align__(16) float ctx[2][256];                // 2KB
    __shared__ __align__(16) float w2s[256];                   // 1KB
    __shared__ __align__(16) float fcws[258];
    __shared__ __align__(16) float ys[2][128];                 // 1KB
    __shared__ float red[16];
    __shared__ float ytil[2];

    const int t = threadIdx.x;
    const int lane = t & 63;
    const int wv = t >> 6;           // wave 0..15
    const int b0 = blockIdx.x * 2;

    // ---- one-time staging
    ((float*)hc2)[t] = 0.f;
    if (t < 256) w2s[t] = w2g[t];
    if (t < 258) fcws[t] = (t < 257) ? fcw[t] : fcb[0];
    if (t < 256) ys[t >> 7][t & 127] = yhist[(size_t)(b0 + (t >> 7)) * NT + (t & 127)];
    // enc -> LDS bf16 (both rows, all 128 steps)
    #pragma unroll
    for (int k = 0; k < 16; ++k) {
        const int idx = t + k * 1024;                 // 0..16383 uint2-chunks
        const int r = idx >> 13, row = (idx >> 6) & 127, eg = idx & 63;
        const float4 v = *(const float4*)(enc + ((size_t)(b0 + r) * NT + row) * NE + eg * 4);
        *(uint2*)&encs[r][row][eg * 4] = pk4(v);
    }
    // pre register slice: thread (s_, jc) holds j = i*32 + jc*4, i<8, both rows
    const int s_ = t >> 3, jc = t & 7;
    uint2 pr0[8], pr1[8];
    {
        const unsigned short* pp = prebf + ((size_t)b0 * NT + s_) * NE + jc * 4;
        #pragma unroll
        for (int i = 0; i < 8; ++i) {
            pr0[i] = *(const uint2*)(pp + i * 32);
            pr1[i] = *(const uint2*)(pp + (size_t)NT * NE + i * 32);
        }
    }
    __syncthreads();

    #pragma unroll 1
    for (int ts = 0; ts < NT; ++ts) {
        // ---- A: prehc partials. wave wv: j-group jg=wv&1 (128 j),
        //      i in [ (wv>>1)*64 + (lane>>5)*32, +32 ). Intra-wave xor-32 combine.
        {
            const int jg = wv & 1;
            const int ib = ((wv >> 1) << 6) + ((lane >> 5) << 5);
            const int jl = (lane & 31) * 4;
            float4 a0 = {0,0,0,0}, a1 = {0,0,0,0};
            const unsigned short* wp = w1bf + (size_t)ib * 256 + jg * 128 + jl;
            #pragma unroll 4
            for (int i = 0; i < 32; ++i) {
                const float4 w4 = unpk(*(const uint2*)(wp + (size_t)i * 256));
                const float2 h2 = *(const float2*)&hc2[ib + i][0];
                fma4(a0, h2.x, w4);
                fma4(a1, h2.y, w4);
            }
            a0.x += __shfl_xor(a0.x, 32); a0.y += __shfl_xor(a0.y, 32);
            a0.z += __shfl_xor(a0.z, 32); a0.w += __shfl_xor(a0.w, 32);
            a1.x += __shfl_xor(a1.x, 32); a1.y += __shfl_xor(a1.y, 32);
            a1.z += __shfl_xor(a1.z, 32); a1.w += __shfl_xor(a1.w, 32);
            if (lane < 32) {
                *(float4*)&part[wv * 256 + jl]       = a0;   // r=0
                *(float4*)&part[wv * 256 + 128 + jl] = a1;   // r=1
            }
        }
        __syncthreads();
        if (t < 512) {        // reduce A: 8 partials per (r,j)
            const int r = t >> 8, j = t & 255, jg = j >> 7, jl = j & 127;
            float s = 0.f;
            #pragma unroll
            for (int k = 0; k < 8; ++k) s += part[(2 * k + jg) * 256 + r * 128 + jl];
            prehc[r][j] = s;
        }
        __syncthreads();

        // ---- B: scores from register-held pre
        {
            float a0 = 0.f, a1 = 0.f;
            #pragma unroll
            for (int i = 0; i < 8; ++i) {
                const int j = i * 32 + jc * 4;
                const float4 wv4 = *(const float4*)&w2s[j];
                const float4 h0 = *(const float4*)&prehc[0][j];
                const float4 h1 = *(const float4*)&prehc[1][j];
                const float4 q0 = unpk(pr0[i]);
                const float4 q1 = unpk(pr1[i]);
                a0 += fast_tanh(q0.x + h0.x) * wv4.x + fast_tanh(q0.y + h0.y) * wv4.y
                    + fast_tanh(q0.z + h0.z) * wv4.z + fast_tanh(q0.w + h0.w) * wv4.w;
                a1 += fast_tanh(q1.x + h1.x) * wv4.x + fast_tanh(q1.y + h1.y) * wv4.y
                    + fast_tanh(q1.z + h1.z) * wv4.z + fast_tanh(q1.w + h1.w) * wv4.w;
            }
            a0 += __shfl_xor(a0, 1); a0 += __shfl_xor(a0, 2); a0 += __shfl_xor(a0, 4);
            a1 += __shfl_xor(a1, 1); a1 += __shfl_xor(a1, 2); a1 += __shfl_xor(a1, 4);
            if (jc == 0) { scores[0][s_] = a0; scores[1][s_] = a1; }
        }
        __syncthreads();

        // ---- softmax in-place (scores -> attn)
        if (t < 128) {
            const int r = t >> 6, l = t & 63;
            const float v0 = scores[r][l], v1 = scores[r][l + 64];
            float m = fmaxf(v0, v1);
            #pragma unroll
            for (int off = 32; off; off >>= 1) m = fmaxf(m, __shfl_xor(m, off));
            const float e0 = __expf(v0 - m), e1 = __expf(v1 - m);
            float sum = e0 + e1;
            #pragma unroll
            for (int off = 32; off; off >>= 1) sum += __shfl_xor(sum, off);
            const float inv = __fdividef(1.f, sum);
            scores[r][l] = e0 * inv;
            scores[r][l + 64] = e1 * inv;
        }
        __syncthreads();

        // ---- C: ctx partials, all 16 s-rows from LDS
        {
            const int r2 = t >> 9, sl = (t >> 6) & 7, e4 = (t & 63) * 4;
            float4 acc = {0.f, 0.f, 0.f, 0.f};
            #pragma unroll
            for (int q = 0; q < 16; ++q) {
                const float a = scores[r2][sl * 16 + q];
                const uint2 ev = *(const uint2*)&encs[r2][sl * 16 + q][e4];
                fma4(acc, a, unpk(ev));
            }
            *(float4*)&part[(sl * 2 + r2) * 256 + e4] = acc;
        }
        __syncthreads();
        if (t < 512) {        // reduce C + y_tilde partial
            const int r = t >> 8, e = t & 255;
            float v = 0.f;
            #pragma unroll
            for (int sl2 = 0; sl2 < 8; ++sl2) v += part[(sl2 * 2 + r) * 256 + e];
            ctx[r][e] = v;
            float p = v * fcws[e];
            #pragma unroll
            for (int off = 32; off; off >>= 1) p += __shfl_xor(p, off);
            if (lane == 0) red[wv] = p;     // waves 0..7
        }
        __syncthreads();

        // ---- E: gate partials. wave wv: K-half ks=wv>>3, col-group cg=wv&7.
        //      lane: 2 cols, both rows, 128 i. Partials 2ks x 2r x 1024 = 16KB.
        {
            if (t < 2)
                ytil[t] = red[4 * t] + red[4 * t + 1] + red[4 * t + 2] + red[4 * t + 3]
                        + ys[t][ts] * fcws[256] + fcws[257];
            const int ks = wv >> 3, cg = wv & 7;
            const int col = cg * 128 + lane * 2;
            float2 c0 = {0.f, 0.f}, c1 = {0.f, 0.f};
            const unsigned short* wp = whhT + (size_t)(ks * 128) * 1024 + col;
            #pragma unroll 8
            for (int i = 0; i < 128; ++i) {
                const unsigned int u = *(const unsigned int*)(wp + (size_t)i * 1024);
                const float w0 = __uint_as_float(u << 16);
                const float w1v = __uint_as_float(u & 0xFFFF0000u);
                const float2 h2 = *(const float2*)&hc2[ks * 128 + i][0];
                c0.x += h2.x * w0; c0.y += h2.x * w1v;
                c1.x += h2.y * w0; c1.y += h2.y * w1v;
            }
            *(float2*)&part[ks * 2048 + col]        = c0;   // r=0
            *(float2*)&part[ks * 2048 + 1024 + col] = c1;   // r=1
        }
        __syncthreads();
        if (t < 512) {        // reduce E (2 K-halves) + LSTM pointwise
            const int r = t >> 8, d = t & 255;
            const float g0 = part[r * 1024 + d]       + part[2048 + r * 1024 + d];
            const float g1 = part[r * 1024 + 256 + d] + part[2048 + r * 1024 + 256 + d];
            const float g2 = part[r * 1024 + 512 + d] + part[2048 + r * 1024 + 512 + d];
            const float g3 = part[r * 1024 + 768 + d] + part[2048 + r * 1024 + 768 + d];
            const float yt = ytil[r];
            const float gi = g0 + yt * wih[d]       + biasg[d];
            const float gf = g1 + yt * wih[256 + d] + biasg[256 + d];
            const float gg = g2 + yt * wih[512 + d] + biasg[512 + d];
            const float go = g3 + yt * wih[768 + d] + biasg[768 + d];
            const float c_old = hc2[256 + d][r];
            const float cn = fast_sigm(gf) * c_old + fast_sigm(gi) * fast_tanh(gg);
            const float hn = fast_sigm(go) * fast_tanh(cn);
            hc2[d][r] = hn;
            hc2[256 + d][r] = cn;
        }
        __syncthreads();
    }

    // ---- final: out[b] = [h, ctx] . fcf_w + fcf_b
    if (t < 512) {
        const int r = t >> 8, j = t & 255;
        float p = hc2[j][r] * fcfw[j] + ctx[r][j] * fcfw[256 + j];
        #pragma unroll
        for (int off = 32; off; off >>= 1) p += __shfl_xor(p, off);
        if (lane == 0) red[wv] = p;
    }
    __syncthreads();
    if (t < 2)
        out[b0 + t] = red[4 * t] + red[4 * t + 1] + red[4 * t + 2] + red[4 * t + 3] + fcfb[0];
}

extern "C" void kernel_launch(void* const* d_in, const int* in_sizes, int n_in,
                              void* d_out, int out_size, void* d_ws, size_t ws_size,
                              hipStream_t stream) {
    (void)in_sizes; (void)n_in; (void)out_size; (void)ws_size;
    const float* enc   = (const float*)d_in[0];   // [512][128][256]
    const float* yhist = (const float*)d_in[1];   // [512][128]
    const float* w1    = (const float*)d_in[2];   // [768][256]
    const float* b1    = (const float*)d_in[3];   // [256]
    const float* w2    = (const float*)d_in[4];   // [256]
    // d_in[5] = attn_b2: softmax-invariant, unused
    const float* wih   = (const float*)d_in[6];   // [1024]
    const float* whh   = (const float*)d_in[7];   // [1024][256]
    const float* bih   = (const float*)d_in[8];   // [1024]
    const float* bhh   = (const float*)d_in[9];   // [1024]
    const float* fcw   = (const float*)d_in[10];  // [257]
    const float* fcb   = (const float*)d_in[11];  // [1]
    const float* fcfw  = (const float*)d_in[12];  // [512]
    const float* fcfb  = (const float*)d_in[13];  // [1]
    float* out = (float*)d_out;

    unsigned short* prebf = (unsigned short*)d_ws;        // 16777216 bf16 (32MB)
    unsigned short* w1bf  = prebf + 16777216;             // 131072 bf16
    unsigned short* whhT  = w1bf + 131072;                // 262144 bf16
    float* biasg = (float*)(whhT + 262144);               // 1024 f

    prep_w1_bias<<<513, 256, 0, stream>>>(w1, bih, bhh, w1bf, biasg);
    transpose_whh_bf<<<64, 256, 0, stream>>>(whh, whhT);
    pre_enc_kernel<<<8192, 256, 0, stream>>>(enc, w1, b1, prebf);
    decoder_main<<<256, 1024, 0, stream>>>(enc, yhist, prebf, w1bf, w2, whhT,
                                           wih, biasg, fcw, fcb, fcfw, fcfb, out);
}

// Round 8
// 3718.039 us; speedup vs baseline: 2.3069x; 2.3069x over previous
//
#include <hip/hip_runtime.h>
#include <hip/hip_bf16.h>

#define NT 128
#define NE 256
#define ND 256

__device__ __forceinline__ float fast_tanh(float x) {
    const float e = __expf(2.f * x);
    return __builtin_fmaf(-2.f, __fdividef(1.f, e + 1.f), 1.f);
}
__device__ __forceinline__ float fast_sigm(float x) {
    return __fdividef(1.f, 1.f + __expf(-x));
}
__device__ __forceinline__ void fma4(float4& a, float s, const float4 b) {
    a.x += s * b.x; a.y += s * b.y; a.z += s * b.z; a.w += s * b.w;
}
__device__ __forceinline__ unsigned short f2bf(float f) {   // RNE
    unsigned int u = __float_as_uint(f);
    return (unsigned short)((u + 0x7FFFu + ((u >> 16) & 1u)) >> 16);
}
// unpack 4 bf16 (packed in uint2) -> float4. elem0 = low half of .x
__device__ __forceinline__ float4 unpk(uint2 u) {
    float4 r;
    r.x = __uint_as_float(u.x << 16);
    r.y = __uint_as_float(u.x & 0xFFFF0000u);
    r.z = __uint_as_float(u.y << 16);
    r.w = __uint_as_float(u.y & 0xFFFF0000u);
    return r;
}
__device__ __forceinline__ uint2 pk4(float4 v) {
    uint2 u;
    u.x = (unsigned int)f2bf(v.x) | ((unsigned int)f2bf(v.y) << 16);
    u.y = (unsigned int)f2bf(v.z) | ((unsigned int)f2bf(v.w) << 16);
    return u;
}

// ---- prep: w1 hc-half -> bf16 (blocks 0..511); bias sum (block 512)
__global__ __launch_bounds__(256) void prep_w1_bias(
    const float* __restrict__ w1, const float* __restrict__ bih,
    const float* __restrict__ bhh, unsigned short* __restrict__ w1bf,
    float* __restrict__ biasg)
{
    const int t = threadIdx.x, blk = blockIdx.x;
    if (blk < 512) {
        const int idx = blk * 256 + t;
        w1bf[idx] = f2bf(w1[idx]);
    } else {
        for (int g = t; g < 1024; g += 256) biasg[g] = bih[g] + bhh[g];
    }
}

// ---- transpose whh[1024][256] -> whhT_bf16[256][1024]
__global__ __launch_bounds__(256) void transpose_whh_bf(
    const float* __restrict__ whh, unsigned short* __restrict__ whhT)
{
    __shared__ float tile[64][65];
    const int t = threadIdx.x;
    const int bi = blockIdx.x >> 2;
    const int bj = blockIdx.x & 3;
    #pragma unroll
    for (int k = 0; k < 16; ++k) {
        const int idx = k * 256 + t, r = idx >> 6, c = idx & 63;
        tile[r][c] = whh[(size_t)(bi * 64 + r) * 256 + bj * 64 + c];
    }
    __syncthreads();
    #pragma unroll
    for (int k = 0; k < 16; ++k) {
        const int idx = k * 256 + t, r = idx >> 6, c = idx & 63;
        whhT[(size_t)(bj * 64 + r) * 1024 + bi * 64 + c] = f2bf(tile[c][r]);
    }
}

// ---- pre[row][j] = b1[j] + sum_i enc[row][i] * attn_w1[512+i][j]; bf16 out
__global__ __launch_bounds__(256) void pre_enc_kernel(
    const float* __restrict__ enc, const float* __restrict__ w1,
    const float* __restrict__ b1, unsigned short* __restrict__ prebf)
{
    __shared__ __align__(16) float encs[8][256];
    const int t = threadIdx.x;
    const size_t r0 = (size_t)blockIdx.x * 8;
    for (int k = t; k < 512; k += 256) {
        const int rl = k >> 6, i4 = (k & 63) * 4;
        *(float4*)&encs[rl][i4] = *(const float4*)(enc + (r0 + rl) * 256 + i4);
    }
    __syncthreads();
    const int rl = t >> 5;
    const int j0 = (t & 31) * 8;
    float4 a0 = *(const float4*)(b1 + j0);
    float4 a1 = *(const float4*)(b1 + j0 + 4);
    const float* wp = w1 + (size_t)512 * 256 + j0;
    #pragma unroll 2
    for (int i = 0; i < 256; i += 4) {
        const float4 e4 = *(const float4*)&encs[rl][i];
        const float* w_i = wp + (size_t)i * 256;
        float4 wa, wb;
        wa = *(const float4*)(w_i);        wb = *(const float4*)(w_i + 4);
        fma4(a0, e4.x, wa); fma4(a1, e4.x, wb);
        wa = *(const float4*)(w_i + 256);  wb = *(const float4*)(w_i + 260);
        fma4(a0, e4.y, wa); fma4(a1, e4.y, wb);
        wa = *(const float4*)(w_i + 512);  wb = *(const float4*)(w_i + 516);
        fma4(a0, e4.z, wa); fma4(a1, e4.z, wb);
        wa = *(const float4*)(w_i + 768);  wb = *(const float4*)(w_i + 772);
        fma4(a0, e4.w, wa); fma4(a1, e4.w, wb);
    }
    unsigned short* op = prebf + (r0 + rl) * 256 + j0;
    const uint2 u0 = pk4(a0), u1 = pk4(a1);
    *(uint2*)op = u0;
    *(uint2*)(op + 4) = u1;
}

// ---- main scan: 256 WGs x 1024 threads, 2 batch rows per WG.
// enc fully in LDS (128KB bf16). pre is STREAMED from L2 each step (bf16,
// 128KB/WG/step, fixed addresses -> L2-resident) -- NOT register-staged:
// 1024-thread WGs pin VGPR=64 on this toolchain (r5/r6/r7 all spilled the
// staged regs to scratch, 18MB/launch). Design now fits 64 VGPRs.
__global__ __launch_bounds__(1024) void decoder_main(
    const float* __restrict__ enc, const float* __restrict__ yhist,
    const unsigned short* __restrict__ prebf,
    const unsigned short* __restrict__ w1bf,
    const float* __restrict__ w2g, const unsigned short* __restrict__ whhT,
    const float* __restrict__ wih, const float* __restrict__ biasg,
    const float* __restrict__ fcw, const float* __restrict__ fcb,
    const float* __restrict__ fcfw, const float* __restrict__ fcfb,
    float* __restrict__ out)
{
    __shared__ __align__(16) unsigned short encs[2][128][256]; // 128KB
    __shared__ __align__(16) float part[4096];                 // 16KB union A/C/E
    __shared__ __align__(16) float hc2[512][2];                // 4KB [i][r]
    __shared__ __align__(16) float prehc[2][256];              // 2KB
    __shared__ __align__(16) float scores[2][128];             // 1KB
    __shared__ __align__(16) float ctx[2][256];                // 2KB
    __shared__ __align__(16) float w2s[256];                   // 1KB
    __shared__ __align__(16) float fcws[258];
    __shared__ __align__(16) float ys[2][128];                 // 1KB
    __shared__ float red[16];
    __shared__ float ytil[2];

    const int t = threadIdx.x;
    const int lane = t & 63;
    const int wv = t >> 6;           // wave 0..15
    const int b0 = blockIdx.x * 2;

    // ---- one-time staging
    ((float*)hc2)[t] = 0.f;
    if (t < 256) w2s[t] = w2g[t];
    if (t < 258) fcws[t] = (t < 257) ? fcw[t] : fcb[0];
    if (t < 256) ys[t >> 7][t & 127] = yhist[(size_t)(b0 + (t >> 7)) * NT + (t & 127)];
    // enc -> LDS bf16 (both rows, all 128 steps)
    #pragma unroll
    for (int k = 0; k < 16; ++k) {
        const int idx = t + k * 1024;                 // 0..16383 uint2-chunks
        const int r = idx >> 13, row = (idx >> 6) & 127, eg = idx & 63;
        const float4 v = *(const float4*)(enc + ((size_t)(b0 + r) * NT + row) * NE + eg * 4);
        *(uint2*)&encs[r][row][eg * 4] = pk4(v);
    }
    // phase-B thread mapping (fixed across steps)
    const int s_ = t >> 3, jc = t & 7;
    const unsigned short* ppre = prebf + ((size_t)b0 * NT + s_) * NE + jc * 4;
    __syncthreads();

    #pragma unroll 1
    for (int ts = 0; ts < NT; ++ts) {
        // ---- A: prehc partials. wave wv: j-group jg=wv&1 (128 j),
        //      i in [ (wv>>1)*64 + (lane>>5)*32, +32 ). Intra-wave xor-32 combine.
        {
            const int jg = wv & 1;
            const int ib = ((wv >> 1) << 6) + ((lane >> 5) << 5);
            const int jl = (lane & 31) * 4;
            float4 a0 = {0,0,0,0}, a1 = {0,0,0,0};
            const unsigned short* wp = w1bf + (size_t)ib * 256 + jg * 128 + jl;
            #pragma unroll 4
            for (int i = 0; i < 32; ++i) {
                const float4 w4 = unpk(*(const uint2*)(wp + (size_t)i * 256));
                const float2 h2 = *(const float2*)&hc2[ib + i][0];
                fma4(a0, h2.x, w4);
                fma4(a1, h2.y, w4);
            }
            a0.x += __shfl_xor(a0.x, 32); a0.y += __shfl_xor(a0.y, 32);
            a0.z += __shfl_xor(a0.z, 32); a0.w += __shfl_xor(a0.w, 32);
            a1.x += __shfl_xor(a1.x, 32); a1.y += __shfl_xor(a1.y, 32);
            a1.z += __shfl_xor(a1.z, 32); a1.w += __shfl_xor(a1.w, 32);
            if (lane < 32) {
                *(float4*)&part[wv * 256 + jl]       = a0;   // r=0
                *(float4*)&part[wv * 256 + 128 + jl] = a1;   // r=1
            }
        }
        __syncthreads();
        if (t < 512) {        // reduce A: 8 partials per (r,j)
            const int r = t >> 8, j = t & 255, jg = j >> 7, jl = j & 127;
            float s = 0.f;
            #pragma unroll
            for (int k = 0; k < 8; ++k) s += part[(2 * k + jg) * 256 + r * 128 + jl];
            prehc[r][j] = s;
        }
        __syncthreads();

        // ---- B: scores. pre streamed from L2 (fixed addr; asm blocks LICM
        //      so the 16 loads are NOT hoisted into spilled registers).
        {
            const unsigned short* pp0 = ppre;
            asm volatile("" : "+v"(pp0));
            const unsigned short* pp1 = pp0 + (size_t)NT * NE;
            float a0 = 0.f, a1 = 0.f;
            #pragma unroll
            for (int i = 0; i < 8; ++i) {
                const int j = i * 32 + jc * 4;
                const float4 wv4 = *(const float4*)&w2s[j];
                const float4 h0 = *(const float4*)&prehc[0][j];
                const float4 h1 = *(const float4*)&prehc[1][j];
                const float4 q0 = unpk(*(const uint2*)(pp0 + i * 32));
                const float4 q1 = unpk(*(const uint2*)(pp1 + i * 32));
                a0 += fast_tanh(q0.x + h0.x) * wv4.x + fast_tanh(q0.y + h0.y) * wv4.y
                    + fast_tanh(q0.z + h0.z) * wv4.z + fast_tanh(q0.w + h0.w) * wv4.w;
                a1 += fast_tanh(q1.x + h1.x) * wv4.x + fast_tanh(q1.y + h1.y) * wv4.y
                    + fast_tanh(q1.z + h1.z) * wv4.z + fast_tanh(q1.w + h1.w) * wv4.w;
            }
            a0 += __shfl_xor(a0, 1); a0 += __shfl_xor(a0, 2); a0 += __shfl_xor(a0, 4);
            a1 += __shfl_xor(a1, 1); a1 += __shfl_xor(a1, 2); a1 += __shfl_xor(a1, 4);
            if (jc == 0) { scores[0][s_] = a0; scores[1][s_] = a1; }
        }
        __syncthreads();

        // ---- softmax in-place (scores -> attn)
        if (t < 128) {
            const int r = t >> 6, l = t & 63;
            const float v0 = scores[r][l], v1 = scores[r][l + 64];
            float m = fmaxf(v0, v1);
            #pragma unroll
            for (int off = 32; off; off >>= 1) m = fmaxf(m, __shfl_xor(m, off));
            const float e0 = __expf(v0 - m), e1 = __expf(v1 - m);
            float sum = e0 + e1;
            #pragma unroll
            for (int off = 32; off; off >>= 1) sum += __shfl_xor(sum, off);
            const float inv = __fdividef(1.f, sum);
            scores[r][l] = e0 * inv;
            scores[r][l + 64] = e1 * inv;
        }
        __syncthreads();

        // ---- C: ctx partials, all 16 s-rows from LDS
        {
            const int r2 = t >> 9, sl = (t >> 6) & 7, e4 = (t & 63) * 4;
            float4 acc = {0.f, 0.f, 0.f, 0.f};
            #pragma unroll
            for (int q = 0; q < 16; ++q) {
                const float a = scores[r2][sl * 16 + q];
                const uint2 ev = *(const uint2*)&encs[r2][sl * 16 + q][e4];
                fma4(acc, a, unpk(ev));
            }
            *(float4*)&part[(sl * 2 + r2) * 256 + e4] = acc;
        }
        __syncthreads();
        if (t < 512) {        // reduce C + y_tilde partial
            const int r = t >> 8, e = t & 255;
            float v = 0.f;
            #pragma unroll
            for (int sl2 = 0; sl2 < 8; ++sl2) v += part[(sl2 * 2 + r) * 256 + e];
            ctx[r][e] = v;
            float p = v * fcws[e];
            #pragma unroll
            for (int off = 32; off; off >>= 1) p += __shfl_xor(p, off);
            if (lane == 0) red[wv] = p;     // waves 0..7
        }
        __syncthreads();

        // ---- E: gate partials. wave wv: i-half ks=wv>>3 (128 i),
        //      col block cg=wv&7 (128 of 1024). lane: i-quarter (lane>>5),
        //      4 cols (8B coalesced load). xor-32 combine -> 16KB partials.
        {
            if (t < 2)
                ytil[t] = red[4 * t] + red[4 * t + 1] + red[4 * t + 2] + red[4 * t + 3]
                        + ys[t][ts] * fcws[256] + fcws[257];
            const int ks = wv >> 3;
            const int cg = wv & 7;
            const int ibase = ks * 128 + (lane >> 5) * 64;
            const int col = cg * 128 + (lane & 31) * 4;
            float4 c0 = {0,0,0,0}, c1 = {0,0,0,0};
            const unsigned short* wp = whhT + (size_t)ibase * 1024 + col;
            #pragma unroll 8
            for (int i = 0; i < 64; ++i) {
                const float4 w4 = unpk(*(const uint2*)(wp + (size_t)i * 1024));
                const float2 h2 = *(const float2*)&hc2[ibase + i][0];
                fma4(c0, h2.x, w4);
                fma4(c1, h2.y, w4);
            }
            c0.x += __shfl_xor(c0.x, 32); c0.y += __shfl_xor(c0.y, 32);
            c0.z += __shfl_xor(c0.z, 32); c0.w += __shfl_xor(c0.w, 32);
            c1.x += __shfl_xor(c1.x, 32); c1.y += __shfl_xor(c1.y, 32);
            c1.z += __shfl_xor(c1.z, 32); c1.w += __shfl_xor(c1.w, 32);
            if (lane < 32) {
                *(float4*)&part[ks * 2048 + col]        = c0;   // r=0
                *(float4*)&part[ks * 2048 + 1024 + col] = c1;   // r=1
            }
        }
        __syncthreads();
        if (t < 512) {        // reduce E (2 i-halves) + LSTM pointwise
            const int r = t >> 8, d = t & 255;
            const float g0 = part[r * 1024 + d]       + part[2048 + r * 1024 + d];
            const float g1 = part[r * 1024 + 256 + d] + part[2048 + r * 1024 + 256 + d];
            const float g2 = part[r * 1024 + 512 + d] + part[2048 + r * 1024 + 512 + d];
            const float g3 = part[r * 1024 + 768 + d] + part[2048 + r * 1024 + 768 + d];
            const float yt = ytil[r];
            const float gi = g0 + yt * wih[d]       + biasg[d];
            const float gf = g1 + yt * wih[256 + d] + biasg[256 + d];
            const float gg = g2 + yt * wih[512 + d] + biasg[512 + d];
            const float go = g3 + yt * wih[768 + d] + biasg[768 + d];
            const float c_old = hc2[256 + d][r];
            const float cn = fast_sigm(gf) * c_old + fast_sigm(gi) * fast_tanh(gg);
            const float hn = fast_sigm(go) * fast_tanh(cn);
            hc2[d][r] = hn;
            hc2[256 + d][r] = cn;
        }
        __syncthreads();
    }

    // ---- final: out[b] = [h, ctx] . fcf_w + fcf_b
    if (t < 512) {
        const int r = t >> 8, j = t & 255;
        float p = hc2[j][r] * fcfw[j] + ctx[r][j] * fcfw[256 + j];
        #pragma unroll
        for (int off = 32; off; off >>= 1) p += __shfl_xor(p, off);
        if (lane == 0) red[wv] = p;
    }
    __syncthreads();
    if (t < 2)
        out[b0 + t] = red[4 * t] + red[4 * t + 1] + red[4 * t + 2] + red[4 * t + 3] + fcfb[0];
}

extern "C" void kernel_launch(void* const* d_in, const int* in_sizes, int n_in,
                              void* d_out, int out_size, void* d_ws, size_t ws_size,
                              hipStream_t stream) {
    (void)in_sizes; (void)n_in; (void)out_size; (void)ws_size;
    const float* enc   = (const float*)d_in[0];   // [512][128][256]
    const float* yhist = (const float*)d_in[1];   // [512][128]
    const float* w1    = (const float*)d_in[2];   // [768][256]
    const float* b1    = (const float*)d_in[3];   // [256]
    const float* w2    = (const float*)d_in[4];   // [256]
    // d_in[5] = attn_b2: softmax-invariant, unused
    const float* wih   = (const float*)d_in[6];   // [1024]
    const float* whh   = (const float*)d_in[7];   // [1024][256]
    const float* bih   = (const float*)d_in[8];   // [1024]
    const float* bhh   = (const float*)d_in[9];   // [1024]
    const float* fcw   = (const float*)d_in[10];  // [257]
    const float* fcb   = (const float*)d_in[11];  // [1]
    const float* fcfw  = (const float*)d_in[12];  // [512]
    const float* fcfb  = (const float*)d_in[13];  // [1]
    float* out = (float*)d_out;

    unsigned short* prebf = (unsigned short*)d_ws;        // 16777216 bf16 (32MB)
    unsigned short* w1bf  = prebf + 16777216;             // 131072 bf16
    unsigned short* whhT  = w1bf + 131072;                // 262144 bf16
    float* biasg = (float*)(whhT + 262144);               // 1024 f

    prep_w1_bias<<<513, 256, 0, stream>>>(w1, bih, bhh, w1bf, biasg);
    transpose_whh_bf<<<64, 256, 0, stream>>>(whh, whhT);
    pre_enc_kernel<<<8192, 256, 0, stream>>>(enc, w1, b1, prebf);
    decoder_main<<<256, 1024, 0, stream>>>(enc, yhist, prebf, w1bf, w2, whhT,
                                           wih, biasg, fcw, fcb, fcfw, fcfb, out);
}

// Round 9
// 3171.246 us; speedup vs baseline: 2.7047x; 1.1724x over previous
//
#include <hip/hip_runtime.h>
#include <hip/hip_bf16.h>

#define NT 128
#define NE 256
#define ND 256

typedef __attribute__((ext_vector_type(8))) short bf16x8;
typedef __attribute__((ext_vector_type(4))) float f32x4;

__device__ __forceinline__ float fast_tanh(float x) {
    const float e = __expf(2.f * x);
    return __builtin_fmaf(-2.f, __fdividef(1.f, e + 1.f), 1.f);
}
__device__ __forceinline__ float fast_sigm(float x) {
    return __fdividef(1.f, 1.f + __expf(-x));
}
__device__ __forceinline__ void fma4(float4& a, float s, const float4 b) {
    a.x += s * b.x; a.y += s * b.y; a.z += s * b.z; a.w += s * b.w;
}
__device__ __forceinline__ unsigned short f2bf(float f) {   // RNE
    unsigned int u = __float_as_uint(f);
    return (unsigned short)((u + 0x7FFFu + ((u >> 16) & 1u)) >> 16);
}
__device__ __forceinline__ float bf2f(unsigned short s) {
    return __uint_as_float(((unsigned int)s) << 16);
}
__device__ __forceinline__ float4 unpk(uint2 u) {
    float4 r;
    r.x = __uint_as_float(u.x << 16);
    r.y = __uint_as_float(u.x & 0xFFFF0000u);
    r.z = __uint_as_float(u.y << 16);
    r.w = __uint_as_float(u.y & 0xFFFF0000u);
    return r;
}
__device__ __forceinline__ uint2 pk4(float4 v) {
    uint2 u;
    u.x = (unsigned int)f2bf(v.x) | ((unsigned int)f2bf(v.y) << 16);
    u.y = (unsigned int)f2bf(v.z) | ((unsigned int)f2bf(v.w) << 16);
    return u;
}

// ---- pack attn_w1 hc-half (rows 0..511) into MFMA B-frag order:
// w1m[((kt*16+nt)*64+l)*8 + j] = W1[kt*32+(l>>4)*8+j][nt*16+(l&15)]
__global__ __launch_bounds__(64) void pack_w1mfma(
    const float* __restrict__ w1, unsigned short* __restrict__ w1m)
{
    const int blk = blockIdx.x;          // kt*16+nt
    const int kt = blk >> 4, nt = blk & 15;
    const int l = threadIdx.x;
    const int kb = kt * 32 + (l >> 4) * 8;
    const int col = nt * 16 + (l & 15);
    float v[8];
    #pragma unroll
    for (int j = 0; j < 8; ++j) v[j] = w1[(size_t)(kb + j) * 256 + col];
    uint4 o;
    o.x = (unsigned int)f2bf(v[0]) | ((unsigned int)f2bf(v[1]) << 16);
    o.y = (unsigned int)f2bf(v[2]) | ((unsigned int)f2bf(v[3]) << 16);
    o.z = (unsigned int)f2bf(v[4]) | ((unsigned int)f2bf(v[5]) << 16);
    o.w = (unsigned int)f2bf(v[6]) | ((unsigned int)f2bf(v[7]) << 16);
    *(uint4*)(w1m + ((size_t)blk * 64 + l) * 8) = o;
}

// ---- pack whh into MFMA B-frag order (B = WhhT[256][1024], WhhT[i][c]=whh[c][i]):
// whhm[((kt*64+nt)*64+l)*8 + j] = whh[nt*16+(l&15)][kt*32+(l>>4)*8+j]
// block 512: biasg = bih + bhh
__global__ __launch_bounds__(64) void pack_whh_bias(
    const float* __restrict__ whh, const float* __restrict__ bih,
    const float* __restrict__ bhh, unsigned short* __restrict__ whhm,
    float* __restrict__ biasg)
{
    const int blk = blockIdx.x;
    const int l = threadIdx.x;
    if (blk < 512) {
        const int kt = blk >> 6, nt = blk & 63;
        const int row = nt * 16 + (l & 15);
        const int kb = kt * 32 + (l >> 4) * 8;
        const float4 lo = *(const float4*)&whh[(size_t)row * 256 + kb];
        const float4 hi = *(const float4*)&whh[(size_t)row * 256 + kb + 4];
        const uint2 a = pk4(lo), b = pk4(hi);
        uint4 o; o.x = a.x; o.y = a.y; o.z = b.x; o.w = b.y;
        *(uint4*)(whhm + ((size_t)blk * 64 + l) * 8) = o;
    } else {
        for (int g = l; g < 1024; g += 64) biasg[g] = bih[g] + bhh[g];
    }
}

// ---- pre[row][j] = b1[j] + sum_i enc[row][i] * attn_w1[512+i][j]; bf16 out
__global__ __launch_bounds__(256) void pre_enc_kernel(
    const float* __restrict__ enc, const float* __restrict__ w1,
    const float* __restrict__ b1, unsigned short* __restrict__ prebf)
{
    __shared__ __align__(16) float encs[8][256];
    const int t = threadIdx.x;
    const size_t r0 = (size_t)blockIdx.x * 8;
    for (int k = t; k < 512; k += 256) {
        const int rl = k >> 6, i4 = (k & 63) * 4;
        *(float4*)&encs[rl][i4] = *(const float4*)(enc + (r0 + rl) * 256 + i4);
    }
    __syncthreads();
    const int rl = t >> 5;
    const int j0 = (t & 31) * 8;
    float4 a0 = *(const float4*)(b1 + j0);
    float4 a1 = *(const float4*)(b1 + j0 + 4);
    const float* wp = w1 + (size_t)512 * 256 + j0;
    #pragma unroll 2
    for (int i = 0; i < 256; i += 4) {
        const float4 e4 = *(const float4*)&encs[rl][i];
        const float* w_i = wp + (size_t)i * 256;
        float4 wa, wb;
        wa = *(const float4*)(w_i);        wb = *(const float4*)(w_i + 4);
        fma4(a0, e4.x, wa); fma4(a1, e4.x, wb);
        wa = *(const float4*)(w_i + 256);  wb = *(const float4*)(w_i + 260);
        fma4(a0, e4.y, wa); fma4(a1, e4.y, wb);
        wa = *(const float4*)(w_i + 512);  wb = *(const float4*)(w_i + 516);
        fma4(a0, e4.z, wa); fma4(a1, e4.z, wb);
        wa = *(const float4*)(w_i + 768);  wb = *(const float4*)(w_i + 772);
        fma4(a0, e4.w, wa); fma4(a1, e4.w, wb);
    }
    unsigned short* op = prebf + (r0 + rl) * 256 + j0;
    const uint2 u0 = pk4(a0), u1 = pk4(a1);
    *(uint2*)op = u0;
    *(uint2*)(op + 4) = u1;
}

// ---- main scan: 256 WGs x 1024 threads, 2 batch rows per WG.
// A and E GEMVs on MFMA (M=2 padded to 16); weights pre-packed in B-frag
// order stream from L2 as coalesced 16B/lane loads. h,c kept bf16 in LDS
// for MFMA A-frags; c kept fp32 separately for the pointwise update.
__global__ __launch_bounds__(1024) void decoder_main(
    const float* __restrict__ enc, const float* __restrict__ yhist,
    const unsigned short* __restrict__ prebf,
    const unsigned short* __restrict__ w1m,
    const float* __restrict__ w2g, const unsigned short* __restrict__ whhm,
    const float* __restrict__ wih, const float* __restrict__ biasg,
    const float* __restrict__ fcw, const float* __restrict__ fcb,
    const float* __restrict__ fcfw, const float* __restrict__ fcfb,
    float* __restrict__ out)
{
    __shared__ __align__(16) unsigned short encs[2][128][256]; // 128KB
    __shared__ __align__(16) float part[4096];                 // 16KB: C partials / E gates
    __shared__ __align__(16) unsigned short hcbf[2][512];      // 2KB bf16 [h(256),c(256)]
    __shared__ __align__(16) float cfs[2][256];                // 2KB fp32 c
    __shared__ __align__(16) float prehc[2][256];              // 2KB
    __shared__ __align__(16) float scores[2][128];             // 1KB
    __shared__ __align__(16) float ctx[2][256];                // 2KB
    __shared__ __align__(16) float w2s[256];                   // 1KB
    __shared__ __align__(16) float fcws[258];
    __shared__ __align__(16) float ys[2][128];                 // 1KB
    __shared__ float red[16];
    __shared__ float ytil[2];

    const int t = threadIdx.x;
    const int lane = t & 63;
    const int wv = t >> 6;           // wave 0..15
    const int b0 = blockIdx.x * 2;

    // ---- one-time staging
    if (t < 512) { ((unsigned int*)hcbf)[t] = 0u; ((float*)cfs)[t] = 0.f; }
    if (t < 256) w2s[t] = w2g[t];
    if (t < 258) fcws[t] = (t < 257) ? fcw[t] : fcb[0];
    if (t < 256) ys[t >> 7][t & 127] = yhist[(size_t)(b0 + (t >> 7)) * NT + (t & 127)];
    #pragma unroll
    for (int k = 0; k < 16; ++k) {
        const int idx = t + k * 1024;                 // 0..16383 uint2-chunks
        const int r = idx >> 13, row = (idx >> 6) & 127, eg = idx & 63;
        const float4 v = *(const float4*)(enc + ((size_t)(b0 + r) * NT + row) * NE + eg * 4);
        *(uint2*)&encs[r][row][eg * 4] = pk4(v);
    }
    // phase-B thread mapping (fixed across steps)
    const int s_ = t >> 3, jc = t & 7;
    const unsigned short* ppre = prebf + ((size_t)b0 * NT + s_) * NE + jc * 4;
    // MFMA lane geometry
    const int arow = lane & 15;                 // M-row this lane feeds
    const bool realrow = arow < 2;
    const int aoff = (lane >> 4) * 8;           // k-offset within K-tile
    const bf16x8* w1m8 = (const bf16x8*)w1m;
    const bf16x8* whm8 = (const bf16x8*)whhm;
    const bf16x8 azero = {0, 0, 0, 0, 0, 0, 0, 0};
    __syncthreads();

    #pragma unroll 1
    for (int ts = 0; ts < NT; ++ts) {
        // ---- A (MFMA): prehc[16x256] = hcbf[16x512(pad)] x W1. wave wv owns ntile wv.
        {
            f32x4 acc = {0.f, 0.f, 0.f, 0.f};
            #pragma unroll 4
            for (int kt = 0; kt < 16; ++kt) {
                bf16x8 a = *(const bf16x8*)&hcbf[arow & 1][kt * 32 + aoff];
                if (!realrow) a = azero;
                const bf16x8 b = w1m8[(kt * 16 + wv) * 64 + lane];
                acc = __builtin_amdgcn_mfma_f32_16x16x32_bf16(a, b, acc, 0, 0, 0);
            }
            if (lane < 16) {
                prehc[0][wv * 16 + lane] = acc[0];
                prehc[1][wv * 16 + lane] = acc[1];
            }
        }
        __syncthreads();

        // ---- B: scores. pre streamed from L2 (asm blocks LICM/hoist-to-spill).
        {
            const unsigned short* pp0 = ppre;
            asm volatile("" : "+v"(pp0));
            const unsigned short* pp1 = pp0 + (size_t)NT * NE;
            float a0 = 0.f, a1 = 0.f;
            #pragma unroll
            for (int i = 0; i < 8; ++i) {
                const int j = i * 32 + jc * 4;
                const float4 wv4 = *(const float4*)&w2s[j];
                const float4 h0 = *(const float4*)&prehc[0][j];
                const float4 h1 = *(const float4*)&prehc[1][j];
                const float4 q0 = unpk(*(const uint2*)(pp0 + i * 32));
                const float4 q1 = unpk(*(const uint2*)(pp1 + i * 32));
                a0 += fast_tanh(q0.x + h0.x) * wv4.x + fast_tanh(q0.y + h0.y) * wv4.y
                    + fast_tanh(q0.z + h0.z) * wv4.z + fast_tanh(q0.w + h0.w) * wv4.w;
                a1 += fast_tanh(q1.x + h1.x) * wv4.x + fast_tanh(q1.y + h1.y) * wv4.y
                    + fast_tanh(q1.z + h1.z) * wv4.z + fast_tanh(q1.w + h1.w) * wv4.w;
            }
            a0 += __shfl_xor(a0, 1); a0 += __shfl_xor(a0, 2); a0 += __shfl_xor(a0, 4);
            a1 += __shfl_xor(a1, 1); a1 += __shfl_xor(a1, 2); a1 += __shfl_xor(a1, 4);
            if (jc == 0) { scores[0][s_] = a0; scores[1][s_] = a1; }
        }
        __syncthreads();

        // ---- softmax in-place
        if (t < 128) {
            const int r = t >> 6, l = t & 63;
            const float v0 = scores[r][l], v1 = scores[r][l + 64];
            float m = fmaxf(v0, v1);
            #pragma unroll
            for (int off = 32; off; off >>= 1) m = fmaxf(m, __shfl_xor(m, off));
            const float e0 = __expf(v0 - m), e1 = __expf(v1 - m);
            float sum = e0 + e1;
            #pragma unroll
            for (int off = 32; off; off >>= 1) sum += __shfl_xor(sum, off);
            const float inv = __fdividef(1.f, sum);
            scores[r][l] = e0 * inv;
            scores[r][l + 64] = e1 * inv;
        }
        __syncthreads();

        // ---- C: ctx partials, 16 s-rows per thread from enc LDS
        {
            const int r2 = t >> 9, sl = (t >> 6) & 7, e4 = (t & 63) * 4;
            float4 acc = {0.f, 0.f, 0.f, 0.f};
            #pragma unroll
            for (int q = 0; q < 16; ++q) {
                const float a = scores[r2][sl * 16 + q];
                const uint2 ev = *(const uint2*)&encs[r2][sl * 16 + q][e4];
                fma4(acc, a, unpk(ev));
            }
            *(float4*)&part[(sl * 2 + r2) * 256 + e4] = acc;
        }
        __syncthreads();
        if (t < 512) {        // reduce C + y_tilde partial
            const int r = t >> 8, e = t & 255;
            float v = 0.f;
            #pragma unroll
            for (int sl2 = 0; sl2 < 8; ++sl2) v += part[(sl2 * 2 + r) * 256 + e];
            ctx[r][e] = v;
            float p = v * fcws[e];
            #pragma unroll
            for (int off = 32; off; off >>= 1) p += __shfl_xor(p, off);
            if (lane == 0) red[wv] = p;     // waves 0..7
        }
        __syncthreads();

        // ---- E (MFMA): gates[16x1024] = h[16x256(pad)] x WhhT. wave wv: ntiles wv*4..+3
        {
            if (t < 2)
                ytil[t] = red[4 * t] + red[4 * t + 1] + red[4 * t + 2] + red[4 * t + 3]
                        + ys[t][ts] * fcws[256] + fcws[257];
            f32x4 e0 = {0.f,0.f,0.f,0.f}, e1 = {0.f,0.f,0.f,0.f};
            f32x4 e2 = {0.f,0.f,0.f,0.f}, e3 = {0.f,0.f,0.f,0.f};
            #pragma unroll 2
            for (int kt = 0; kt < 8; ++kt) {
                bf16x8 a = *(const bf16x8*)&hcbf[arow & 1][kt * 32 + aoff];
                if (!realrow) a = azero;
                const int base = (kt * 64 + wv * 4) * 64 + lane;
                const bf16x8 bq0 = whm8[base];
                const bf16x8 bq1 = whm8[base + 64];
                const bf16x8 bq2 = whm8[base + 128];
                const bf16x8 bq3 = whm8[base + 192];
                e0 = __builtin_amdgcn_mfma_f32_16x16x32_bf16(a, bq0, e0, 0, 0, 0);
                e1 = __builtin_amdgcn_mfma_f32_16x16x32_bf16(a, bq1, e1, 0, 0, 0);
                e2 = __builtin_amdgcn_mfma_f32_16x16x32_bf16(a, bq2, e2, 0, 0, 0);
                e3 = __builtin_amdgcn_mfma_f32_16x16x32_bf16(a, bq3, e3, 0, 0, 0);
            }
            if (lane < 16) {
                const int nb = wv * 64 + lane;          // col base for q=0
                part[nb]           = e0[0]; part[1024 + nb]      = e0[1];
                part[nb + 16]      = e1[0]; part[1024 + nb + 16] = e1[1];
                part[nb + 32]      = e2[0]; part[1024 + nb + 32] = e2[1];
                part[nb + 48]      = e3[0]; part[1024 + nb + 48] = e3[1];
            }
        }
        __syncthreads();
        if (t < 512) {        // LSTM pointwise
            const int r = t >> 8, d = t & 255;
            const int gb = r * 1024;
            const float yt = ytil[r];
            const float gi = part[gb + d]       + yt * wih[d]       + biasg[d];
            const float gf = part[gb + 256 + d] + yt * wih[256 + d] + biasg[256 + d];
            const float gg = part[gb + 512 + d] + yt * wih[512 + d] + biasg[512 + d];
            const float go = part[gb + 768 + d] + yt * wih[768 + d] + biasg[768 + d];
            const float c_old = cfs[r][d];
            const float cn = fast_sigm(gf) * c_old + fast_sigm(gi) * fast_tanh(gg);
            const float hn = fast_sigm(go) * fast_tanh(cn);
            cfs[r][d] = cn;
            hcbf[r][d] = f2bf(hn);
            hcbf[r][256 + d] = f2bf(cn);
        }
        __syncthreads();
    }

    // ---- final: out[b] = [h, ctx] . fcf_w + fcf_b
    if (t < 512) {
        const int r = t >> 8, j = t & 255;
        float p = bf2f(hcbf[r][j]) * fcfw[j] + ctx[r][j] * fcfw[256 + j];
        #pragma unroll
        for (int off = 32; off; off >>= 1) p += __shfl_xor(p, off);
        if (lane == 0) red[wv] = p;
    }
    __syncthreads();
    if (t < 2)
        out[b0 + t] = red[4 * t] + red[4 * t + 1] + red[4 * t + 2] + red[4 * t + 3] + fcfb[0];
}

extern "C" void kernel_launch(void* const* d_in, const int* in_sizes, int n_in,
                              void* d_out, int out_size, void* d_ws, size_t ws_size,
                              hipStream_t stream) {
    (void)in_sizes; (void)n_in; (void)out_size; (void)ws_size;
    const float* enc   = (const float*)d_in[0];   // [512][128][256]
    const float* yhist = (const float*)d_in[1];   // [512][128]
    const float* w1    = (const float*)d_in[2];   // [768][256]
    const float* b1    = (const float*)d_in[3];   // [256]
    const float* w2    = (const float*)d_in[4];   // [256]
    // d_in[5] = attn_b2: softmax-invariant, unused
    const float* wih   = (const float*)d_in[6];   // [1024]
    const float* whh   = (const float*)d_in[7];   // [1024][256]
    const float* bih   = (const float*)d_in[8];   // [1024]
    const float* bhh   = (const float*)d_in[9];   // [1024]
    const float* fcw   = (const float*)d_in[10];  // [257]
    const float* fcb   = (const float*)d_in[11];  // [1]
    const float* fcfw  = (const float*)d_in[12];  // [512]
    const float* fcfb  = (const float*)d_in[13];  // [1]
    float* out = (float*)d_out;

    unsigned short* prebf = (unsigned short*)d_ws;        // 16777216 bf16 (32MB)
    unsigned short* w1m   = prebf + 16777216;             // 131072 bf16 (256KB)
    unsigned short* whhm  = w1m + 131072;                 // 262144 bf16 (512KB)
    float* biasg = (float*)(whhm + 262144);               // 1024 f

    pack_w1mfma<<<256, 64, 0, stream>>>(w1, w1m);
    pack_whh_bias<<<513, 64, 0, stream>>>(whh, bih, bhh, whhm, biasg);
    pre_enc_kernel<<<8192, 256, 0, stream>>>(enc, w1, b1, prebf);
    decoder_main<<<256, 1024, 0, stream>>>(enc, yhist, prebf, w1m, w2, whhm,
                                           wih, biasg, fcw, fcb, fcfw, fcfb, out);
}